// Round 4
// baseline (127.131 us; speedup 1.0000x reference)
//
#include <hip/hip_runtime.h>
#include <hip/hip_bf16.h>

#define N_Q   25000
#define M_S   25000
#define C_INV 128

typedef unsigned short ushortT;
typedef unsigned short us8 __attribute__((ext_vector_type(8)));
typedef unsigned short us4 __attribute__((ext_vector_type(4)));
typedef short s8v __attribute__((ext_vector_type(8)));
typedef float f32x4 __attribute__((ext_vector_type(4)));

__device__ __forceinline__ float b2f(ushortT u) {
    unsigned v = ((unsigned)u) << 16;
    return __builtin_bit_cast(float, v);
}
__device__ __forceinline__ ushortT f2b(float f) {
    __hip_bfloat16 h = __float2bfloat16(f);
    return __builtin_bit_cast(ushortT, h);
}

// ---------------- kernel 1: x fp32 -> bf16 ----------------
__global__ void k_convert_x(const float* __restrict__ x, ushortT* __restrict__ xb) {
    int i = blockIdx.x * 256 + threadIdx.x;
    const int n4 = (M_S * C_INV) / 4;
    if (i >= n4) return;
    float4 v = ((const float4*)x)[i];
    us4 o;
    o[0] = f2b(v.x); o[1] = f2b(v.y); o[2] = f2b(v.z); o[3] = f2b(v.w);
    ((us4*)xb)[i] = o;
}

// ---------------- kernel 2: W fp32 -> permuted-K fragment-major bf16 ----------------
// K padded to 2048. K-order p = ci*256 + l_src*4 + r  ->  (k = (l_src>>4)*4 + r,
// c = ci*16 + (l_src&15)), zero for k==15 (pad).
// wfrag elem o = ((ks*8 + db)*64 + lane)*8 + j  holds  W_perm[ks*32 + (lane>>4)*8 + j][db*16 + (lane&15)].
__global__ void k_build_wfrag2(const float* __restrict__ W, ushortT* __restrict__ wf) {
    int o = blockIdx.x * 256 + threadIdx.x;
    if (o >= 262144) return;                 // 2048 * 128
    int j   = o & 7;
    int l   = (o >> 3) & 63;
    int db  = (o >> 9) & 7;
    int ks  = o >> 12;                       // 0..63
    int p   = ks * 32 + ((l >> 4) * 8) + j;  // 0..2047
    int ci  = p >> 8;
    int rem = p & 255;
    int ls  = rem >> 2;
    int r   = rem & 3;
    int k   = (ls >> 4) * 4 + r;
    int c   = ci * 16 + (ls & 15);
    int d   = db * 16 + (l & 15);
    wf[o] = (k < 15) ? f2b(W[((size_t)k * 128 + c) * 128 + d]) : (ushortT)0;
}

// ---------------- fused kernel: Q-tile 32, 1024 threads, wf in LDS ----------------
__global__ __launch_bounds__(1024, 4) void k_fused(
    const float* __restrict__ qp, const float* __restrict__ sp,
    const int* __restrict__ nb, const float* __restrict__ kp,
    const ushortT* __restrict__ xbf, const ushortT* __restrict__ wfrag,
    float* __restrict__ out)
{
    // LDS carve: 131072 (s_wf) + 16384 (s_w) + 4096 (s_idx) = 151552 B
    __shared__ __align__(16) char smem[151552];
    ushortT* s_wf  = (ushortT*)smem;                       // [32 q][2048 p] bf16, XOR-swizzled rows
    ushortT* s_w   = (ushortT*)(smem + 131072);            // [16 q][4 hb][16 k][8 h] bf16
    int*     s_idx = (int*)(smem + 131072 + 16384);        // [32 q][32 h]
    float*   s_out = (float*)(smem + 131072);              // 16384 B, aliases s_w+s_idx (dead then)

    const int t   = threadIdx.x;
    const int l   = t & 63;
    const int w   = t >> 6;          // wave 0..15
    const int blk = blockIdx.x;

    for (int half = 0; half < 2; ++half) {
        __syncthreads();   // half 0: no-op hazard; half 1: stage-B reads of s_w complete

        // ---- Stage A for 16 q: thread = (q = t>>6, h = (t>>1)&31, khalf = t&1) ----
        {
            const int q  = t >> 6;
            const int h  = (t >> 1) & 31;
            const int kh = t & 1;
            const int qg = blk * 32 + half * 16 + q;
            const int qc = (qg < N_Q) ? qg : 0;
            const float qx = qp[qc * 3 + 0], qy = qp[qc * 3 + 1], qz = qp[qc * 3 + 2];
            int idx = (qg < N_Q) ? nb[qg * 32 + h] : M_S;
            const bool valid = ((unsigned)idx < (unsigned)M_S);
            const int idc = valid ? idx : 0;
            if (kh == 0) s_idx[(half * 16 + q) * 32 + h] = idc;
            float px, py, pz;
            if (valid) { px = sp[idc * 3]; py = sp[idc * 3 + 1]; pz = sp[idc * 3 + 2]; }
            else       { px = 1e6f; py = 1e6f; pz = 1e6f; }
            const float rx = px - qx, ry = py - qy, rz = pz - qz;
            #pragma unroll
            for (int kk = 0; kk < 8; ++kk) {
                const int k = kh * 8 + kk;
                float wv = 0.0f;
                if (k < 15) {
                    const float dx = rx - kp[k * 3 + 0];
                    const float dy = ry - kp[k * 3 + 1];
                    const float dz = rz - kp[k * 3 + 2];
                    const float d2 = dx * dx + dy * dy + dz * dz;
                    wv = 1.0f - sqrtf(d2) * (1.0f / 1.2f);
                    wv = (wv > 0.0f) ? wv : 0.0f;
                }
                s_w[q * 512 + (h >> 3) * 128 + k * 8 + (h & 7)] = f2b(wv);
            }
        }
        __syncthreads();

        // ---- Stage B: 16 q x 8 ci over 16 waves x 8 iters, barrier-free ----
        // wave: q = half*16 + it*2 + (w>>3), ci = w&7.
        // A = w[k=l&15][h=(l>>4)*8+j]; B = x[idx[h]][ci*16+(l&15)] gathered direct from global.
        for (int it = 0; it < 8; ++it) {
            const int qL   = half * 16 + it * 2 + (w >> 3);
            const int ci   = w & 7;
            const int h0   = (l >> 4) * 8;
            const int4 ia  = *(const int4*)&s_idx[qL * 32 + h0];
            const int4 ib  = *(const int4*)&s_idx[qL * 32 + h0 + 4];
            const int cofs = ci * 16 + (l & 15);
            us8 bx;
            bx[0] = xbf[(size_t)ia.x * 128 + cofs];
            bx[1] = xbf[(size_t)ia.y * 128 + cofs];
            bx[2] = xbf[(size_t)ia.z * 128 + cofs];
            bx[3] = xbf[(size_t)ia.w * 128 + cofs];
            bx[4] = xbf[(size_t)ib.x * 128 + cofs];
            bx[5] = xbf[(size_t)ib.y * 128 + cofs];
            bx[6] = xbf[(size_t)ib.z * 128 + cofs];
            bx[7] = xbf[(size_t)ib.w * 128 + cofs];
            const s8v bfr = __builtin_bit_cast(s8v, bx);
            const s8v afr = *(const s8v*)(s_w + (qL & 15) * 512 + (l >> 4) * 128 + (l & 15) * 8);
            f32x4 d = __builtin_amdgcn_mfma_f32_16x16x32_bf16(afr, bfr, (f32x4){0.f, 0.f, 0.f, 0.f}, 0, 0, 0);
            us4 o4;
            o4[0] = f2b(d[0]); o4[1] = f2b(d[1]); o4[2] = f2b(d[2]); o4[3] = f2b(d[3]);
            const unsigned byteoff = (unsigned)qL * 4096u
                                   + ((((unsigned)ci * 512u) + ((unsigned)l * 8u)) ^ (((unsigned)qL & 7u) << 4));
            *(us4*)(smem + byteoff) = o4;      // s_wf base == smem
        }
    }
    __syncthreads();   // all s_wf writes complete; s_w/s_idx dead

    // ---- zero s_out (aliases s_w region) ----
    ((f32x4*)s_out)[t] = (f32x4){0.f, 0.f, 0.f, 0.f};
    __syncthreads();

    // ---- Stage C: out[32 q][128 d] = wf[32][2048] @ W_perm[2048][128], K-split across waves ----
    // wave: ko = w>>3 (even/odd K-steps), n = w&7 (d-chunk). Each B-fragment loaded once.
    {
        const int ko = w >> 3;
        const int n  = w & 7;
        f32x4 acc0 = {0.f, 0.f, 0.f, 0.f};
        f32x4 acc1 = {0.f, 0.f, 0.f, 0.f};
        #pragma unroll 4
        for (int tt = 0; tt < 32; ++tt) {
            const int ks = tt * 2 + ko;
            const s8v b = *(const s8v*)(wfrag + ((size_t)(ks * 8 + n) * 64 + l) * 8);
            const unsigned inner = (((unsigned)ks * 64u) + (((unsigned)(l >> 4)) * 16u))
                                 ^ ((((unsigned)l & 7u)) << 4);
            const s8v a0 = *(const s8v*)(smem + (unsigned)(l & 15) * 4096u + inner);
            const s8v a1 = *(const s8v*)(smem + (unsigned)(16 + (l & 15)) * 4096u + inner);
            acc0 = __builtin_amdgcn_mfma_f32_16x16x32_bf16(a0, b, acc0, 0, 0, 0);
            acc1 = __builtin_amdgcn_mfma_f32_16x16x32_bf16(a1, b, acc1, 0, 0, 0);
        }
        #pragma unroll
        for (int r = 0; r < 4; ++r) {
            const int row = (l >> 4) * 4 + r;
            const int d   = n * 16 + (l & 15);
            atomicAdd(&s_out[row * 128 + d],        acc0[r]);
            atomicAdd(&s_out[(16 + row) * 128 + d], acc1[r]);
        }
    }
    __syncthreads();

    // ---- write out ----
    {
        const int q  = t >> 5;
        const int i  = t & 31;
        const int qg = blk * 32 + q;
        if (qg < N_Q)
            ((float4*)(out + (size_t)qg * 128))[i] = ((const float4*)s_out)[q * 32 + i];
    }
}

extern "C" void kernel_launch(void* const* d_in, const int* in_sizes, int n_in,
                              void* d_out, int out_size, void* d_ws, size_t ws_size,
                              hipStream_t stream) {
    const float* x  = (const float*)d_in[0];
    const float* qp = (const float*)d_in[1];
    const float* sp = (const float*)d_in[2];
    const int*   nb = (const int*)d_in[3];
    const float* kp = (const float*)d_in[4];
    const float* W  = (const float*)d_in[5];
    float* out = (float*)d_out;

    ushortT* xbf    = (ushortT*)d_ws;                                   // 6.4 MB
    ushortT* wfrag2 = (ushortT*)((char*)d_ws + (size_t)M_S * C_INV * 2); // 512 KB

    k_convert_x<<<3125, 256, 0, stream>>>(x, xbf);
    k_build_wfrag2<<<1024, 256, 0, stream>>>(W, wfrag2);

    const int nblk = (N_Q + 31) / 32;   // 782
    k_fused<<<nblk, 1024, 0, stream>>>(qp, sp, nb, kp, xbf, wfrag2, out);
}

// Round 5
// 81.143 us; speedup vs baseline: 1.5668x; 1.5668x over previous
//
#include <hip/hip_runtime.h>
#include <hip/hip_bf16.h>

#define N_Q   25000
#define M_S   25000
#define C_INV 128

typedef unsigned short ushortT;
typedef unsigned short us8 __attribute__((ext_vector_type(8)));
typedef unsigned short us4 __attribute__((ext_vector_type(4)));
typedef short s8v __attribute__((ext_vector_type(8)));
typedef float f32x4 __attribute__((ext_vector_type(4)));

#define GAS __attribute__((address_space(1)))
#define LAS __attribute__((address_space(3)))

__device__ __forceinline__ float b2f(ushortT u) {
    unsigned v = ((unsigned)u) << 16;
    return __builtin_bit_cast(float, v);
}
__device__ __forceinline__ ushortT f2b(float f) {
    __hip_bfloat16 h = __float2bfloat16(f);
    return __builtin_bit_cast(ushortT, h);
}

// ---------------- kernel 1: x fp32 -> bf16 ----------------
__global__ void k_convert_x(const float* __restrict__ x, ushortT* __restrict__ xb) {
    int i = blockIdx.x * 256 + threadIdx.x;
    const int n4 = (M_S * C_INV) / 4;
    if (i >= n4) return;
    float4 v = ((const float4*)x)[i];
    us4 o;
    o[0] = f2b(v.x); o[1] = f2b(v.y); o[2] = f2b(v.z); o[3] = f2b(v.w);
    ((us4*)xb)[i] = o;
}

// ---------------- kernel 2: W fp32 -> permuted-K fragment-major bf16 (K padded 2048) ----------------
// p = ci*256 + ls*4 + r  ->  (k = (ls>>4)*4 + r, c = ci*16 + (ls&15)), zero for k==15.
// wfrag elem o = ((ks*8 + db)*64 + lane)*8 + j holds W_perm[ks*32 + (lane>>4)*8 + j][db*16 + (lane&15)].
__global__ void k_build_wfrag2(const float* __restrict__ W, ushortT* __restrict__ wf) {
    int o = blockIdx.x * 256 + threadIdx.x;
    if (o >= 262144) return;                 // 2048 * 128
    int j   = o & 7;
    int l   = (o >> 3) & 63;
    int db  = (o >> 9) & 7;
    int ks  = o >> 12;                       // 0..63
    int p   = ks * 32 + ((l >> 4) * 8) + j;  // 0..2047
    int ci  = p >> 8;
    int rem = p & 255;
    int ls  = rem >> 2;
    int r   = rem & 3;
    int k   = (ls >> 4) * 4 + r;
    int c   = ci * 16 + (ls & 15);
    int d   = db * 16 + (l & 15);
    wf[o] = (k < 15) ? f2b(W[((size_t)k * 128 + c) * 128 + d]) : (ushortT)0;
}

// ---------------- kernel 2b: old wfrag layout (fallback path only) ----------------
__global__ void k_build_wfrag(const float* __restrict__ W, ushortT* __restrict__ wf) {
    int o = blockIdx.x * 256 + threadIdx.x;
    if (o >= 1920 * 128) return;
    int j  = o & 7;
    int l  = (o >> 3) & 63;
    int db = (o >> 9) & 7;
    int ks = o >> 12;
    int r  = ks * 32 + ((l >> 4) * 8) + j;
    int d  = db * 16 + (l & 15);
    wf[o] = f2b(W[r * 128 + d]);
}

// ================= K1 v5: stages A+B, register gather, fragment-major wf out =================
__global__ __launch_bounds__(512, 4) void k_ab(
    const float* __restrict__ qp, const float* __restrict__ sp,
    const int* __restrict__ nb, const float* __restrict__ kp,
    const ushortT* __restrict__ xbf, ushortT* __restrict__ wf_out)
{
    __shared__ __align__(16) ushortT s_w[16 * 512];   // 16 KB fragment layout [q][(h>>3)*128 + k*8 + (h&7)]
    __shared__ int s_idx[16 * 32];                    //  2 KB

    const int t   = threadIdx.x;
    const int l   = t & 63;
    const int w   = t >> 6;          // wave 0..7
    const int blk = blockIdx.x;

    // ---- Phase A: thread = (q = t>>5, h = t&31) ----
    {
        const int q  = t >> 5;
        const int h  = t & 31;
        const int qg = blk * 16 + q;
        const int qc = (qg < N_Q) ? qg : (N_Q - 1);
        const float qx = qp[qc * 3 + 0], qy = qp[qc * 3 + 1], qz = qp[qc * 3 + 2];
        int idx = (qg < N_Q) ? nb[qg * 32 + h] : M_S;
        const bool valid = ((unsigned)idx < (unsigned)M_S);
        const int idc = valid ? idx : 0;
        s_idx[q * 32 + h] = idc;
        float px, py, pz;
        if (valid) { px = sp[idc * 3]; py = sp[idc * 3 + 1]; pz = sp[idc * 3 + 2]; }
        else       { px = 1e6f; py = 1e6f; pz = 1e6f; }
        const float rx = px - qx, ry = py - qy, rz = pz - qz;
        #pragma unroll
        for (int k = 0; k < 15; ++k) {
            const float dx = rx - kp[k * 3 + 0];
            const float dy = ry - kp[k * 3 + 1];
            const float dz = rz - kp[k * 3 + 2];
            const float d2 = dx * dx + dy * dy + dz * dz;
            float wv = 1.0f - sqrtf(d2) * (1.0f / 1.2f);
            wv = (wv > 0.0f) ? wv : 0.0f;
            s_w[q * 512 + (h >> 3) * 128 + k * 8 + (h & 7)] = f2b(wv);
        }
        s_w[q * 512 + (h >> 3) * 128 + 15 * 8 + (h & 7)] = 0;
    }
    __syncthreads();

    // ---- preload: this wave's 2 q's: A-fragments + row indices into registers ----
    const int c0 = l & 15;
    const int hg = l >> 4;

    s8v af[2];
    int ridx[2][8];
    #pragma unroll
    for (int qi = 0; qi < 2; ++qi) {
        const int q = w * 2 + qi;
        af[qi] = *(const s8v*)(s_w + q * 512 + hg * 128 + c0 * 8);
        #pragma unroll
        for (int j = 0; j < 8; ++j)
            ridx[qi][j] = s_idx[q * 32 + hg * 8 + j];
    }

    us4* wfo = (us4*)wf_out;

    // ---- Phase B: register gather + 8 MFMAs per q, coalesced fragment-major stores ----
    #pragma unroll
    for (int qi = 0; qi < 2; ++qi) {
        const int qrow = blk * 16 + w * 2 + qi;
        const ushortT* rp[8];
        #pragma unroll
        for (int j = 0; j < 8; ++j)
            rp[j] = xbf + (size_t)ridx[qi][j] * 128 + c0;

        us8 xr[8];   // xr[ci][j] = x[idx[hg*8+j]][ci*16 + c0]
        #pragma unroll
        for (int j = 0; j < 8; ++j) {
            #pragma unroll
            for (int ci = 0; ci < 8; ++ci)
                xr[ci][j] = rp[j][ci * 16];
        }
        #pragma unroll
        for (int ci = 0; ci < 8; ++ci) {
            f32x4 d = __builtin_amdgcn_mfma_f32_16x16x32_bf16(
                af[qi], __builtin_bit_cast(s8v, xr[ci]), (f32x4){0.f, 0.f, 0.f, 0.f}, 0, 0, 0);
            us4 o;
            o[0] = f2b(d[0]); o[1] = f2b(d[1]); o[2] = f2b(d[2]); o[3] = f2b(d[3]);
            wfo[(size_t)qrow * 512 + ci * 64 + l] = o;   // 512B contiguous per wave-store
        }
    }
}

// ================= K2 v5: out[25024x128] = wf[25024x2048(perm)] @ W_perm, Q-tile 64 =================
__global__ __launch_bounds__(512, 4) void k_gemm(
    const ushortT* __restrict__ wf, const ushortT* __restrict__ wfrag,
    float* __restrict__ out)
{
    __shared__ __align__(16) ushortT sA[2][8192];   // 16 KB each: 64q x 128 elems (4 ks), XOR-swizzled

    const int t   = threadIdx.x;
    const int l   = t & 63;
    const int w   = t >> 6;          // 0..7
    const int blk = blockIdx.x;
    const int qg  = w >> 2;          // 0..1
    const int n0  = (w & 3) * 2;     // 0,2,4,6

    auto stage = [&](int c4, int buf) {
        #pragma unroll
        for (int u = 0; u < 2; ++u) {
            const int s    = u * 512 + t;
            const int q    = s >> 4;
            const int part = s & 15;
            const ushortT* src = wf + (size_t)(blk * 64 + q) * 2048 + c4 * 128
                               + ((part ^ (q & 7)) * 8);
            __builtin_amdgcn_global_load_lds((const GAS unsigned int*)(const void*)src,
                                             (LAS unsigned int*)(void*)(&sA[buf][(size_t)s * 8]),
                                             16, 0, 0);
        }
    };

    f32x4 a00 = {0.f,0.f,0.f,0.f}, a01 = {0.f,0.f,0.f,0.f};
    f32x4 a10 = {0.f,0.f,0.f,0.f}, a11 = {0.f,0.f,0.f,0.f};

    stage(0, 0);
    __syncthreads();

    for (int c4 = 0; c4 < 16; ++c4) {
        if (c4 < 15) stage(c4 + 1, (c4 + 1) & 1);
        const ushortT* A = sA[c4 & 1];
        const int q0 = qg * 32 + (l & 15);
        const int q1 = q0 + 16;
        #pragma unroll
        for (int kk = 0; kk < 4; ++kk) {
            const int ks = c4 * 4 + kk;
            const s8v b0 = *(const s8v*)(wfrag + ((size_t)(ks * 8 + n0    ) * 64 + l) * 8);
            const s8v b1 = *(const s8v*)(wfrag + ((size_t)(ks * 8 + n0 + 1) * 64 + l) * 8);
            const int eo = kk * 32 + (l >> 4) * 8;
            const s8v av0 = *(const s8v*)(A + q0 * 128 + (eo ^ ((q0 & 7) * 8)));
            const s8v av1 = *(const s8v*)(A + q1 * 128 + (eo ^ ((q1 & 7) * 8)));
            a00 = __builtin_amdgcn_mfma_f32_16x16x32_bf16(av0, b0, a00, 0, 0, 0);
            a01 = __builtin_amdgcn_mfma_f32_16x16x32_bf16(av0, b1, a01, 0, 0, 0);
            a10 = __builtin_amdgcn_mfma_f32_16x16x32_bf16(av1, b0, a10, 0, 0, 0);
            a11 = __builtin_amdgcn_mfma_f32_16x16x32_bf16(av1, b1, a11, 0, 0, 0);
        }
        __syncthreads();
    }

    #pragma unroll
    for (int r = 0; r < 4; ++r) {
        const int qa = blk * 64 + qg * 32 + (l >> 4) * 4 + r;
        const int qb = qa + 16;
        const int d0 = n0 * 16 + (l & 15);
        if (qa < N_Q) {
            out[(size_t)qa * 128 + d0]      = a00[r];
            out[(size_t)qa * 128 + d0 + 16] = a01[r];
        }
        if (qb < N_Q) {
            out[(size_t)qb * 128 + d0]      = a10[r];
            out[(size_t)qb * 128 + d0 + 16] = a11[r];
        }
    }
}

// ================= fallback: round-1 fused kernel (used if ws too small) =================
__global__ __launch_bounds__(256, 2) void k_main_fb(
    const float* __restrict__ qp, const float* __restrict__ sp,
    const int* __restrict__ nb, const float* __restrict__ kp,
    const ushortT* __restrict__ xbf, const ushortT* __restrict__ wfrag,
    float* __restrict__ out)
{
    __shared__ ushortT s_w[16][32][16];
    __shared__ int s_idx[16][32];
    __shared__ __align__(16) ushortT s_wf[16][1928];

    const int t   = threadIdx.x;
    const int blk = blockIdx.x;

    {
        const int q  = t >> 4;
        const int h0 = t & 15;
        const int qg = blk * 16 + q;
        const int qc = (qg < N_Q) ? qg : 0;
        const float qx = qp[qc * 3 + 0], qy = qp[qc * 3 + 1], qz = qp[qc * 3 + 2];
        #pragma unroll
        for (int i = 0; i < 2; ++i) {
            const int h  = h0 + 16 * i;
            int idx = (qg < N_Q) ? nb[qg * 32 + h] : M_S;
            const bool valid = ((unsigned)idx < (unsigned)M_S);
            s_idx[q][h] = valid ? idx : 0;
            float px, py, pz;
            if (valid) { px = sp[idx * 3]; py = sp[idx * 3 + 1]; pz = sp[idx * 3 + 2]; }
            else       { px = 1e6f; py = 1e6f; pz = 1e6f; }
            const float rx = px - qx, ry = py - qy, rz = pz - qz;
            #pragma unroll
            for (int k = 0; k < 15; ++k) {
                const float dx = rx - kp[k * 3 + 0];
                const float dy = ry - kp[k * 3 + 1];
                const float dz = rz - kp[k * 3 + 2];
                const float d2 = dx * dx + dy * dy + dz * dz;
                float wv = 1.0f - sqrtf(d2) * (1.0f / 1.2f);
                wv = (wv > 0.0f) ? wv : 0.0f;
                s_w[q][h][k] = f2b(wv);
            }
            s_w[q][h][15] = 0;
        }
    }
    __syncthreads();

    {
        const int q  = t >> 4;
        const int c0 = (t & 15) * 8;
        float acc[15][8];
        #pragma unroll
        for (int k = 0; k < 15; ++k)
            #pragma unroll
            for (int j = 0; j < 8; ++j) acc[k][j] = 0.0f;

        int idx0 = s_idx[q][0];
        us8 xv = *(const us8*)(xbf + (size_t)idx0 * C_INV + c0);
        for (int h = 0; h < 32; ++h) {
            const us8 xc = xv;
            if (h < 31) {
                int idn = s_idx[q][h + 1];
                xv = *(const us8*)(xbf + (size_t)idn * C_INV + c0);
            }
            const us8 w0 = *(const us8*)&s_w[q][h][0];
            const us8 w1 = *(const us8*)&s_w[q][h][8];
            float xf[8];
            #pragma unroll
            for (int j = 0; j < 8; ++j) xf[j] = b2f(xc[j]);
            #pragma unroll
            for (int k = 0; k < 15; ++k) {
                const float wk = b2f((k < 8) ? w0[k] : w1[k - 8]);
                #pragma unroll
                for (int j = 0; j < 8; ++j) acc[k][j] += wk * xf[j];
            }
        }
        #pragma unroll
        for (int k = 0; k < 15; ++k) {
            us8 o;
            #pragma unroll
            for (int j = 0; j < 8; ++j) o[j] = f2b(acc[k][j]);
            *(us8*)&s_wf[q][k * C_INV + c0] = o;
        }
    }
    __syncthreads();

    {
        const int lane = t & 63;
        const int wv   = t >> 6;
        const int db0  = wv * 2;
        const int arow = lane & 15;
        const int kofs = (lane >> 4) * 8;
        f32x4 acc0 = {0.f, 0.f, 0.f, 0.f};
        f32x4 acc1 = {0.f, 0.f, 0.f, 0.f};
        #pragma unroll 4
        for (int ks = 0; ks < 60; ++ks) {
            s8v a  = *(const s8v*)&s_wf[arow][ks * 32 + kofs];
            s8v b0 = *(const s8v*)(wfrag + ((size_t)(ks * 8 + db0) * 64 + lane) * 8);
            s8v b1 = *(const s8v*)(wfrag + ((size_t)(ks * 8 + db0 + 1) * 64 + lane) * 8);
            acc0 = __builtin_amdgcn_mfma_f32_16x16x32_bf16(a, b0, acc0, 0, 0, 0);
            acc1 = __builtin_amdgcn_mfma_f32_16x16x32_bf16(a, b1, acc1, 0, 0, 0);
        }
        #pragma unroll
        for (int r = 0; r < 4; ++r) {
            const int q  = (lane >> 4) * 4 + r;
            const int qg = blk * 16 + q;
            if (qg < N_Q) {
                out[(size_t)qg * 128 + db0 * 16 + (lane & 15)]       = acc0[r];
                out[(size_t)qg * 128 + (db0 + 1) * 16 + (lane & 15)] = acc1[r];
            }
        }
    }
}

extern "C" void kernel_launch(void* const* d_in, const int* in_sizes, int n_in,
                              void* d_out, int out_size, void* d_ws, size_t ws_size,
                              hipStream_t stream) {
    const float* x  = (const float*)d_in[0];
    const float* qp = (const float*)d_in[1];
    const float* sp = (const float*)d_in[2];
    const int*   nb = (const int*)d_in[3];
    const float* kp = (const float*)d_in[4];
    const float* W  = (const float*)d_in[5];
    float* out = (float*)d_out;

    const size_t xbf_b   = (size_t)M_S * C_INV * 2;        // 6,400,000
    const size_t wfrag_b = (size_t)2048 * 128 * 2;         // 524,288
    const size_t wf_b    = (size_t)25024 * 2048 * 2;       // 102,498,304

    ushortT* xbf   = (ushortT*)d_ws;
    ushortT* wfrag = (ushortT*)((char*)d_ws + xbf_b);
    ushortT* wfbuf = (ushortT*)((char*)d_ws + xbf_b + wfrag_b);

    k_convert_x<<<3125, 256, 0, stream>>>(x, xbf);

    if (ws_size >= xbf_b + wfrag_b + wf_b) {
        k_build_wfrag2<<<1024, 256, 0, stream>>>(W, wfrag);
        k_ab<<<(N_Q + 15) / 16, 512, 0, stream>>>(qp, sp, nb, kp, xbf, wfbuf);
        k_gemm<<<(N_Q + 63) / 64, 512, 0, stream>>>(wfbuf, wfrag, out);
    } else {
        k_build_wfrag<<<960, 256, 0, stream>>>(W, wfrag);
        k_main_fb<<<(N_Q + 15) / 16, 256, 0, stream>>>(qp, sp, nb, kp, xbf, wfrag, out);
    }
}